// Round 1
// baseline (34.470 us; speedup 1.0000x reference)
//
#include <hip/hip_runtime.h>
#include <math.h>

#define N_ELEM 8388608
#define MLE_EPS 1e-5f

// Stage 1: grid-stride partial sums. 4 elements per thread per iteration,
// all loads vectorized (float4 x2 for pred_params, float4 tte, int4 alive).
__global__ __launch_bounds__(256) void mle_partial_kernel(
    const float* __restrict__ pred,   // (N,2) interleaved: mu, log_sigma
    const float* __restrict__ tte,    // (N,)
    const int*   __restrict__ alive,  // (N,)
    float* __restrict__ partials,
    int n)
{
    const float inv_sqrt2    = 0.7071067811865476f;
    const float half_log_2pi = 0.9189385332046727f;

    const float4* __restrict__ p4 = (const float4*)pred;
    const float4* __restrict__ t4 = (const float4*)tte;
    const int4*   __restrict__ a4 = (const int4*)alive;

    const int n4 = n >> 2;
    const int stride = gridDim.x * blockDim.x;
    float acc = 0.0f;

    for (int i = blockIdx.x * blockDim.x + threadIdx.x; i < n4; i += stride) {
        float4 pa = p4[2 * i];       // mu0 ls0 mu1 ls1
        float4 pb = p4[2 * i + 1];   // mu2 ls2 mu3 ls3
        float4 t  = t4[i];
        int4   a  = a4[i];

        float mu[4] = {pa.x, pa.z, pb.x, pb.z};
        float ls[4] = {pa.y, pa.w, pb.y, pb.w};
        float tt[4] = {t.x, t.y, t.z, t.w};
        int   al[4] = {a.x, a.y, a.z, a.w};

        #pragma unroll
        for (int j = 0; j < 4; ++j) {
            float lt        = __logf(tt[j]);          // log(tte), tte > 0
            float inv_sigma = __expf(-ls[j]);         // 1/sigma without divide
            float z  = (lt - mu[j]) * inv_sigma * inv_sqrt2;
            // 1 - cdf + eps == 0.5*erfc(z) + eps
            float loss_alive = -__logf(0.5f * erfcf(z) + MLE_EPS);

            float lx = __logf(tt[j] + MLE_EPS);
            float d  = lx - mu[j];
            // log_prob = -lx - log(sigma) - c - (lx-mu)^2 / (2 sigma^2)
            float log_prob = -lx - ls[j] - half_log_2pi
                             - 0.5f * d * d * inv_sigma * inv_sigma;
            float loss = al[j] ? loss_alive : -log_prob;
            acc += loss;
        }
    }

    // wave64 shuffle reduce
    #pragma unroll
    for (int off = 32; off > 0; off >>= 1)
        acc += __shfl_down(acc, off);

    __shared__ float wsum[4];               // 256 threads = 4 waves
    if ((threadIdx.x & 63) == 0) wsum[threadIdx.x >> 6] = acc;
    __syncthreads();
    if (threadIdx.x == 0)
        partials[blockIdx.x] = wsum[0] + wsum[1] + wsum[2] + wsum[3];
}

// Stage 2: deterministic single-block finish; writes mean to d_out[0].
__global__ __launch_bounds__(256) void mle_final_kernel(
    const float* __restrict__ partials, int nblocks, float* __restrict__ out)
{
    float acc = 0.0f;
    for (int i = threadIdx.x; i < nblocks; i += 256)
        acc += partials[i];

    #pragma unroll
    for (int off = 32; off > 0; off >>= 1)
        acc += __shfl_down(acc, off);

    __shared__ float wsum[4];
    if ((threadIdx.x & 63) == 0) wsum[threadIdx.x >> 6] = acc;
    __syncthreads();
    if (threadIdx.x == 0) {
        float s = wsum[0] + wsum[1] + wsum[2] + wsum[3];
        out[0] = s / (float)N_ELEM;
    }
}

extern "C" void kernel_launch(void* const* d_in, const int* in_sizes, int n_in,
                              void* d_out, int out_size, void* d_ws, size_t ws_size,
                              hipStream_t stream) {
    const float* pred  = (const float*)d_in[0];
    const float* tte   = (const float*)d_in[1];
    const int*   alive = (const int*)d_in[2];
    float* out = (float*)d_out;
    float* partials = (float*)d_ws;

    const int n = in_sizes[1];          // N
    const int nblocks = 2048;

    mle_partial_kernel<<<nblocks, 256, 0, stream>>>(pred, tte, alive, partials, n);
    mle_final_kernel<<<1, 256, 0, stream>>>(partials, nblocks, out);
}

// Round 2
// 31.773 us; speedup vs baseline: 1.0849x; 1.0849x over previous
//
#include <hip/hip_runtime.h>
#include <math.h>

#define N_ELEM 8388608
#define MLE_EPS 1e-5f

// Abramowitz-Stegun 7.1.26 erfc: abs error <= 1.5e-7, ~13 VALU ops.
__device__ __forceinline__ float fast_erfc(float x) {
    float ax = __builtin_fabsf(x);
    float t  = __builtin_amdgcn_rcpf(__builtin_fmaf(0.3275911f, ax, 1.0f));
    float p  = 1.061405429f;
    p = __builtin_fmaf(p, t, -1.453152027f);
    p = __builtin_fmaf(p, t,  1.421413741f);
    p = __builtin_fmaf(p, t, -0.284496736f);
    p = __builtin_fmaf(p, t,  0.254829592f);
    p = p * t;
    float e = __expf(-ax * ax);
    float r = p * e;                       // erfc(ax) for ax >= 0
    return (x < 0.0f) ? (2.0f - r) : r;
}

__device__ __forceinline__ float mle_elem(float mu, float ls, float t, int al) {
    const float inv_sqrt2    = 0.7071067811865476f;
    const float half_log_2pi = 0.9189385332046727f;

    float lt        = __logf(t);
    float inv_sigma = __expf(-ls);
    float z         = (lt - mu) * inv_sigma * inv_sqrt2;
    float loss_alive = -__logf(__builtin_fmaf(0.5f, fast_erfc(z), MLE_EPS));

    float lx = __logf(t + MLE_EPS);
    float d  = lx - mu;
    // loss_dead = -log_prob = lx + ls + c + (lx-mu)^2/(2 sigma^2)
    float loss_dead = lx + ls + half_log_2pi
                      + 0.5f * d * d * inv_sigma * inv_sigma;
    return al ? loss_alive : loss_dead;
}

__global__ __launch_bounds__(256) void mle_partial_kernel(
    const float* __restrict__ pred,   // (N,2) interleaved: mu, log_sigma
    const float* __restrict__ tte,    // (N,)
    const int*   __restrict__ alive,  // (N,)
    float* __restrict__ partials,
    int n)
{
    const float4* __restrict__ p4 = (const float4*)pred;
    const float4* __restrict__ t4 = (const float4*)tte;
    const int4*   __restrict__ a4 = (const int4*)alive;

    const int n4      = n >> 2;
    const int stride  = gridDim.x * blockDim.x;
    const int tid     = blockIdx.x * blockDim.x + threadIdx.x;
    float acc = 0.0f;

    if (n4 == stride * 4) {
        // Compile-time trip count: full unroll, all loads hoisted for ILP.
        #pragma unroll
        for (int k = 0; k < 4; ++k) {
            int i = tid + k * stride;
            float4 pa = p4[2 * i];
            float4 pb = p4[2 * i + 1];
            float4 t  = t4[i];
            int4   a  = a4[i];
            acc += mle_elem(pa.x, pa.y, t.x, a.x);
            acc += mle_elem(pa.z, pa.w, t.y, a.y);
            acc += mle_elem(pb.x, pb.y, t.z, a.z);
            acc += mle_elem(pb.z, pb.w, t.w, a.w);
        }
    } else {
        for (int i = tid; i < n4; i += stride) {
            float4 pa = p4[2 * i];
            float4 pb = p4[2 * i + 1];
            float4 t  = t4[i];
            int4   a  = a4[i];
            acc += mle_elem(pa.x, pa.y, t.x, a.x);
            acc += mle_elem(pa.z, pa.w, t.y, a.y);
            acc += mle_elem(pb.x, pb.y, t.z, a.z);
            acc += mle_elem(pb.z, pb.w, t.w, a.w);
        }
    }

    #pragma unroll
    for (int off = 32; off > 0; off >>= 1)
        acc += __shfl_down(acc, off);

    __shared__ float wsum[4];
    if ((threadIdx.x & 63) == 0) wsum[threadIdx.x >> 6] = acc;
    __syncthreads();
    if (threadIdx.x == 0)
        partials[blockIdx.x] = wsum[0] + wsum[1] + wsum[2] + wsum[3];
}

__global__ __launch_bounds__(256) void mle_final_kernel(
    const float* __restrict__ partials, int nblocks, float* __restrict__ out)
{
    float acc = 0.0f;
    for (int i = threadIdx.x; i < nblocks; i += 256)
        acc += partials[i];

    #pragma unroll
    for (int off = 32; off > 0; off >>= 1)
        acc += __shfl_down(acc, off);

    __shared__ float wsum[4];
    if ((threadIdx.x & 63) == 0) wsum[threadIdx.x >> 6] = acc;
    __syncthreads();
    if (threadIdx.x == 0) {
        float s = wsum[0] + wsum[1] + wsum[2] + wsum[3];
        out[0] = s / (float)N_ELEM;
    }
}

extern "C" void kernel_launch(void* const* d_in, const int* in_sizes, int n_in,
                              void* d_out, int out_size, void* d_ws, size_t ws_size,
                              hipStream_t stream) {
    const float* pred  = (const float*)d_in[0];
    const float* tte   = (const float*)d_in[1];
    const int*   alive = (const int*)d_in[2];
    float* out = (float*)d_out;
    float* partials = (float*)d_ws;

    const int n = in_sizes[1];
    const int nblocks = 2048;

    mle_partial_kernel<<<nblocks, 256, 0, stream>>>(pred, tte, alive, partials, n);
    mle_final_kernel<<<1, 256, 0, stream>>>(partials, nblocks, out);
}